// Round 1
// baseline (104.665 us; speedup 1.0000x reference)
//
#include <hip/hip_runtime.h>
#include <stdint.h>

// Problem constants (fixed by the reference)
#define BQ    32     // batch
#define NSUB  512    // subjects per image
#define NDET  1024   // subjects + objects
#define NCLS  30     // labels 0..29
#define KSLOT 30     // 15 subject + 15 object output slots
#define BCAP  96     // max active boxes per (image,class); mean ~27
#define NTHR  1024   // 16 waves
#define NWAVE 16

#pragma clang fp contract(off)

typedef unsigned long long u64;

// Single fused kernel: one block per image.
//  Phase 0: every block scans ALL boxes (512 KB, L2-resident) -> exact global
//           max_coord (fmax is order-independent) — dissolves the grid-wide
//           dependency that forced the old 3-kernel split.
//  Phase 1: bucket this image's active detections by class into LDS.
//  Phase 2: per-wave per-class greedy NMS (verbatim decision arithmetic from
//           the verified kernel; classes independent since cross-class IoU is
//           exactly 0 under the per-class offset). 16 waves x 2 rounds = 30+.
//  Phase 3: waves 0/1 do the 15-round argmax select per side, reading keys AND
//           boxes straight from LDS (label = bucket class, score = key bits).
__global__ __launch_bounds__(NTHR, 1) void fused_nms_kernel(
    const float* __restrict__ sb, const float* __restrict__ ss,
    const int*   __restrict__ sl,
    const float* __restrict__ ob, const float* __restrict__ os,
    const int*   __restrict__ ol,
    float* __restrict__ out)
{
#pragma clang fp contract(off)
    const int b = blockIdx.x, t = threadIdx.x;
    const int lane = t & 63, w = t >> 6;

    __shared__ u64    bkey[NCLS][BCAP];      // 23040 B  bucket keys
    __shared__ float4 bbox[NCLS][BCAP];      // 46080 B  bucket boxes
    __shared__ u64    skey[NWAVE][BCAP];     // 12288 B  per-wave sorted keys
    __shared__ float4 sbox[NWAVE][BCAP];     // 24576 B  per-wave sorted boxes
    __shared__ u64    outk[2][NCLS * 15];    //  7200 B  kept keys  (side 0=sub)
    __shared__ float4 outbx[2][NCLS * 15];   // 14400 B  kept boxes
    __shared__ int    lcnt[NCLS];
    __shared__ float  wred[NWAVE];
    __shared__ float  gmaxs;                 // total ~124.8 KB LDS

    const float4* sb4 = (const float4*)sb;
    const float4* ob4 = (const float4*)ob;

    // ---- Phase 0: exact global max over ALL images' boxes (jnp.max(boxes)) --
    float m = -__builtin_inff();
    for (int i = t; i < BQ * NSUB; i += NTHR) {
        float4 a = sb4[i], c4 = ob4[i];
        m = fmaxf(m, fmaxf(fmaxf(a.x, a.y), fmaxf(a.z, a.w)));
        m = fmaxf(m, fmaxf(fmaxf(c4.x, c4.y), fmaxf(c4.z, c4.w)));
    }
    for (int off = 32; off; off >>= 1) m = fmaxf(m, __shfl_xor(m, off));
    if (lane == 0) wred[w] = m;
    if (t < NCLS) lcnt[t] = 0;
    __syncthreads();                         // publishes wred + lcnt init
    if (t == 0) {
        float mm = wred[0];
        for (int i = 1; i < NWAVE; ++i) mm = fmaxf(mm, wred[i]);
        gmaxs = mm;
    }

    // ---- Phase 1: bucket this image's detections by class (LDS atomics) ----
    {
        float4 bx; float sc; int lb;
        if (t < NSUB) {                      // waves 0-7: subjects (uniform)
            bx = sb4[b * NSUB + t];
            sc = ss[b * NSUB + t];
            lb = sl[b * NSUB + t];
        } else {                             // waves 8-15: objects
            int j = t - NSUB;
            bx = ob4[b * NSUB + j];
            sc = os[b * NSUB + j];
            lb = ol[b * NSUB + j];
        }
        if (sc >= 0.2f) {                    // active = score >= SCORE_THRESH
            int pos = atomicAdd(&lcnt[lb], 1);
            if (pos < BCAP) {
                // key = (score bits, 1023 - concat_idx): unique, desc order ==
                // stable sort by -score (lower original idx wins ties)
                bkey[lb][pos] = ((u64)__float_as_uint(sc) << 32) | (u64)(1023 - t);
                bbox[lb][pos] = bx;
            }
        }
    }
    __syncthreads();                         // buckets + gmaxs visible
    const float mco = gmaxs + 1.0f;          // (max_coord + 1.0)

    // ---- Phase 2: per-wave per-class single-wave greedy NMS ----
    for (int rr = 0; rr < 2; ++rr) {
        const int c = w + NWAVE * rr;        // wave-uniform
        if (c >= NCLS) break;
        int cnt = lcnt[c]; if (cnt > BCAP) cnt = BCAP;
        const float offc = (float)c * mco;

        // speculative LDS loads (masked by cnt below; garbage safe)
        u64    K1 = bkey[c][lane];
        float4 B1 = bbox[c][lane];
        u64 K2 = 0; float4 B2 = make_float4(0.f, 0.f, 0.f, 0.f);
        if (lane < BCAP - 64) {
            K2 = bkey[c][64 + lane];
            B2 = bbox[c][64 + lane];
        }

        // rank-sort desc by unique key; scatter key AND box by rank
        {
            int r = 0;
            for (int l = 0; l < cnt; ++l) r += (bkey[c][l] > K1) ? 1 : 0;
            if (lane < cnt) { skey[w][r] = K1; sbox[w][r] = B1; }
        }
        if (cnt > 64) {                      // rare second chunk
            int e = 64 + lane;
            int r = 0;
            for (int l = 0; l < cnt; ++l) r += (bkey[c][l] > K2) ? 1 : 0;
            if (e < cnt) { skey[w][r] = K2; sbox[w][r] = B2; }
        }
        __threadfence_block();               // in-wave LDS RAW

        const int  lim1  = (cnt < 64) ? cnt : 64;
        const bool have1 = (lane < lim1);
        u64 SK1 = have1 ? skey[w][lane] : 0;
        int idx1 = 1023 - (int)(unsigned)(SK1 & 0xffffffffull);
        float4 bj1 = have1 ? sbox[w][lane] : make_float4(0.f, 0.f, 0.f, 0.f);
        const bool have2 = (64 + lane) < cnt;
        u64 SK2 = 0; int idx2 = 0; float4 bj2 = make_float4(0.f, 0.f, 0.f, 0.f);
        if (cnt > 64) {
            SK2 = have2 ? skey[w][64 + lane] : 0;
            idx2 = 1023 - (int)(unsigned)(SK2 & 0xffffffffull);
            if (have2) bj2 = sbox[w][64 + lane];
        }

        // chunk A: overlap masks + ballot resolve (verbatim decision body)
        float j0 = bj1.x + offc, j1 = bj1.y + offc;
        float j2v = bj1.z + offc, j3 = bj1.w + offc;
        float aj = (j2v - j0) * (j3 - j1);
        u64 ov = 0;
        for (int l = 0; l < lim1; ++l) {
            float4 bl = sbox[w][l];
            float i0 = bl.x + offc, i1 = bl.y + offc;
            float i2 = bl.z + offc, i3 = bl.w + offc;
            float ai = (i2 - i0) * (i3 - i1);
            if (have1 && l < lane) {
                float ltx = fmaxf(i0, j0), lty = fmaxf(i1, j1);
                float rbx = fminf(i2, j2v), rby = fminf(i3, j3);
                float wx = fmaxf(rbx - ltx, 0.0f), wy = fmaxf(rby - lty, 0.0f);
                float inter = wx * wy;
                float iou = inter / ((ai + aj) - inter);
                if (iou > 0.5f) ov |= (1ull << l);
            }
        }
        bool sup1 = !have1;
        for (int l = 0; l < lim1; ++l) {     // invariant: final for lanes <= l
            u64 bal = __ballot(sup1);
            if (!((bal >> l) & 1ull)) sup1 = sup1 || (((ov >> l) & 1ull) != 0ull);
        }
        const bool kept1 = have1 && !sup1;
        const u64 keptA = __ballot(kept1);

        // chunk B (rare): entries 64..cnt-1
        bool kept2 = false;
        if (cnt > 64) {
            float k0 = bj2.x + offc, k1 = bj2.y + offc;
            float k2 = bj2.z + offc, k3 = bj2.w + offc;
            float ak = (k2 - k0) * (k3 - k1);
            bool sup2 = !have2;
            for (int l = 0; l < 64; ++l) {   // vs kept chunk-A entries
                if ((keptA >> l) & 1ull) {
                    float4 bl = sbox[w][l];
                    float i0 = bl.x + offc, i1 = bl.y + offc;
                    float i2 = bl.z + offc, i3 = bl.w + offc;
                    float ai = (i2 - i0) * (i3 - i1);
                    if (!sup2) {
                        float ltx = fmaxf(i0, k0), lty = fmaxf(i1, k1);
                        float rbx = fminf(i2, k2), rby = fminf(i3, k3);
                        float wx = fmaxf(rbx - ltx, 0.0f), wy = fmaxf(rby - lty, 0.0f);
                        float inter = wx * wy;
                        float iou = inter / ((ai + ak) - inter);
                        if (iou > 0.5f) sup2 = true;
                    }
                }
            }
            u64 ov2 = 0;
            const int lim2 = cnt - 64;
            for (int l = 0; l < lim2; ++l) {
                float4 bl = sbox[w][64 + l];
                float i0 = bl.x + offc, i1 = bl.y + offc;
                float i2 = bl.z + offc, i3 = bl.w + offc;
                float ai = (i2 - i0) * (i3 - i1);
                if (have2 && l < lane) {
                    float ltx = fmaxf(i0, k0), lty = fmaxf(i1, k1);
                    float rbx = fminf(i2, k2), rby = fminf(i3, k3);
                    float wx = fmaxf(rbx - ltx, 0.0f), wy = fmaxf(rby - lty, 0.0f);
                    float inter = wx * wy;
                    float iou = inter / ((ai + ak) - inter);
                    if (iou > 0.5f) ov2 |= (1ull << l);
                }
            }
            for (int l = 0; l < lim2; ++l) {
                u64 bal = __ballot(sup2);
                if (!((bal >> l) & 1ull)) sup2 = sup2 || (((ov2 >> l) & 1ull) != 0ull);
            }
            kept2 = have2 && !sup2;
        }

        // write first <=15 kept subject/object (key, box) for this class to LDS
        const bool s1 = kept1 && (idx1 < NSUB), o1 = kept1 && (idx1 >= NSUB);
        const bool s2 = kept2 && (idx2 < NSUB), o2 = kept2 && (idx2 >= NSUB);
        const u64 mS1 = __ballot(s1), mS2 = __ballot(s2);
        const u64 mO1 = __ballot(o1), mO2 = __ballot(o2);
        const u64 ltm = (1ull << lane) - 1ull;
        u64*    skp = &outk[0][c * 15];  float4* sbp = &outbx[0][c * 15];
        u64*    okp = &outk[1][c * 15];  float4* obp = &outbx[1][c * 15];
        if (s1) { int p = (int)__popcll(mS1 & ltm); if (p < 15) { skp[p] = SK1; sbp[p] = bj1; } }
        if (s2) { int p = (int)__popcll(mS1) + (int)__popcll(mS2 & ltm); if (p < 15) { skp[p] = SK2; sbp[p] = bj2; } }
        if (o1) { int p = (int)__popcll(mO1 & ltm); if (p < 15) { okp[p] = SK1; obp[p] = bj1; } }
        if (o2) { int p = (int)__popcll(mO1) + (int)__popcll(mO2 & ltm); if (p < 15) { okp[p] = SK2; obp[p] = bj2; } }
        int tS = (int)(__popcll(mS1) + __popcll(mS2)); if (tS > 15) tS = 15;
        int tO = (int)(__popcll(mO1) + __popcll(mO2)); if (tO > 15) tO = 15;
        if (lane >= tS && lane < 15) skp[lane] = 0;   // key 0 = empty slot
        if (lane >= tO && lane < 15) okp[lane] = 0;
    }
    __syncthreads();                         // out-lists complete

    // ---- Phase 3: per-side top-15 via register argmax (waves 0 and 1) ----
    if (w < 2) {
        const int side = w;                  // 0 = subjects, 1 = objects
        float* outB = out;                   // [32][30][4]
        float* outS = out + BQ * KSLOT * 4;  // 3840
        float* outL = outS + BQ * KSLOT;     // 4800
        float* outN = outL + BQ * KSLOT;     // 5760
        float* outV = outN + BQ;             // 5792

        const u64*    src  = outk[side];
        const float4* srcb = outbx[side];
        u64 kk[8];                           // strided: lane + 64*i (covers 450)
        #pragma unroll
        for (int i = 0; i < 8; ++i) {
            int p = lane + 64 * i;
            kk[i] = (p < NCLS * 15) ? src[p] : 0;
        }
        int nvalid = 0;
        for (int r = 0; r < 15; ++r) {       // 15 argmax rounds
            u64 lm = 0;
            #pragma unroll
            for (int i = 0; i < 8; ++i) lm = (kk[i] > lm) ? kk[i] : lm;
            u64 gm = lm;
            for (int off = 32; off; off >>= 1) {
                u64 o = __shfl_xor(gm, off);
                if (o > gm) gm = o;
            }
            int p = b * KSLOT + (side ? (15 + r) : r);
            if (gm == 0) {                   // no more candidates: empty slot
                if (lane == 0) {
                    *(float4*)(outB + (size_t)p * 4) = make_float4(0.f, 0.f, 0.f, 0.f);
                    outS[p] = 0.0f; outL[p] = -1.0f; outV[p] = 0.0f;
                }
            } else {
                u64 win = __ballot(lm == gm);          // keys unique if nonzero
                int wl = (int)__ffsll(win) - 1;
                if (lane == wl) {
                    int sp = 0;                        // slot of gm (static idx)
                    #pragma unroll
                    for (int i = 0; i < 8; ++i) if (kk[i] == gm) sp = lane + 64 * i;
                    #pragma unroll
                    for (int i = 0; i < 8; ++i) if (kk[i] == gm) kk[i] = 0;  // consume
                    float4 bx = srcb[sp];              // box carried through LDS
                    float score = __uint_as_float((unsigned)(gm >> 32)); // exact
                    int cls = sp / 15;                 // label = bucket class
                    *(float4*)(outB + (size_t)p * 4) = bx;
                    outS[p] = score;
                    outL[p] = (float)cls;
                    outV[p] = 1.0f;
                }
                nvalid++;                              // uniform across lanes
            }
        }
        if (side == 0 && lane == 0) outN[b] = (float)nvalid; // = min(total_s,15)
    }
}

extern "C" void kernel_launch(void* const* d_in, const int* in_sizes, int n_in,
                              void* d_out, int out_size, void* d_ws, size_t ws_size,
                              hipStream_t stream) {
    const float* sb = (const float*)d_in[0];
    const float* ss = (const float*)d_in[1];
    const int*   sl = (const int*)d_in[2];
    const float* ob = (const float*)d_in[3];
    const float* os = (const float*)d_in[4];
    const int*   ol = (const int*)d_in[5];

    // fully fused: one launch, no workspace round-trips, no inter-kernel hops
    fused_nms_kernel<<<dim3(BQ), dim3(NTHR), 0, stream>>>(
        sb, ss, sl, ob, os, ol, (float*)d_out);
}

// Round 2
// 86.847 us; speedup vs baseline: 1.2052x; 1.2052x over previous
//
#include <hip/hip_runtime.h>
#include <stdint.h>

// Problem constants (fixed by the reference)
#define BQ    32     // batch
#define NSUB  512    // subjects per image
#define NDET  1024   // subjects + objects
#define NCLS  30     // labels 0..29
#define KSLOT 30     // 15 subject + 15 object output slots
#define BCAP  96     // max active boxes per (image,class); mean ~27

#pragma clang fp contract(off)

typedef unsigned long long u64;

// ---------------- Kernel 1: bucketize + per-image box max ------------------
// One block per image. Boxes/keys go STRAIGHT to ws bucket slots (registers
// -> global, fire-and-forget). Bucket order nondeterministic (LDS atomics) but
// kernel 2 rank-sorts by the unique key, so results are order-independent.
__global__ __launch_bounds__(512) void bucket_kernel(
    const float* __restrict__ sb, const float* __restrict__ ss,
    const int*   __restrict__ sl,
    const float* __restrict__ ob, const float* __restrict__ os,
    const int*   __restrict__ ol,
    float* __restrict__ pmax, int* __restrict__ cnts,
    u64* __restrict__ bkeys, float4* __restrict__ bboxes)
{
    const int b = blockIdx.x, t = threadIdx.x;
    const int lane = t & 63, w = t >> 6;
    __shared__ int   lcnt[NCLS];
    __shared__ float wred[8];

    if (t < NCLS) lcnt[t] = 0;

    // one coalesced load round: box+score+label for subject t and object t
    float4 bxs = *(const float4*)(sb + (size_t)(b * NSUB + t) * 4);
    float4 bxo = *(const float4*)(ob + (size_t)(b * NSUB + t) * 4);
    float scs = ss[b * NSUB + t];  int lbs = sl[b * NSUB + t];
    float sco = os[b * NSUB + t];  int lbo = ol[b * NSUB + t];

    // per-image max (exact; fmax associative)
    float m = fmaxf(fmaxf(fmaxf(bxs.x, bxs.y), fmaxf(bxs.z, bxs.w)),
                    fmaxf(fmaxf(bxo.x, bxo.y), fmaxf(bxo.z, bxo.w)));
    for (int off = 32; off; off >>= 1) m = fmaxf(m, __shfl_xor(m, off));
    if (lane == 0) wred[w] = m;
    __syncthreads();                       // also publishes lcnt init
    if (t == 0) {
        float mm = wred[0];
        for (int i = 1; i < 8; ++i) mm = fmaxf(mm, wred[i]);
        pmax[b] = mm;
    }

    // bucket active detections by class; write key+box straight to ws
    if (scs >= 0.2f) {                     // active = score >= SCORE_THRESH
        int pos = atomicAdd(&lcnt[lbs], 1);
        if (pos < BCAP) {
            size_t s = ((size_t)b * NCLS + lbs) * BCAP + pos;
            bkeys[s]  = ((u64)__float_as_uint(scs) << 32) | (u64)(1023 - t);
            bboxes[s] = bxs;
        }
    }
    if (sco >= 0.2f) {
        int pos = atomicAdd(&lcnt[lbo], 1);
        if (pos < BCAP) {
            size_t s = ((size_t)b * NCLS + lbo) * BCAP + pos;
            bkeys[s]  = ((u64)__float_as_uint(sco) << 32) | (u64)(1023 - (512 + t));
            bboxes[s] = bxo;
        }
    }
    __syncthreads();
    if (t < NCLS) {
        int c = lcnt[t];
        cnts[b * NCLS + t] = (c < BCAP) ? c : BCAP;
    }
}

// ------- Kernel 2: per-(class,image) single-wave greedy NMS ----------------
// All global loads issued speculatively up front (one latency hop); boxes are
// carried with keys through the rank-sort, so no post-sort gather.
// Cross-class IoU is exactly 0 (per-class offset separates boxes by more than
// any extent) => classes independent (verified absmax 0.0 across sessions).
// NEW vs verified R0: kept BOXES are written alongside kept keys so the select
// kernel never touches the original detection arrays.
__global__ __launch_bounds__(64) void nms_class_kernel(
    const float* __restrict__ pmax, const int* __restrict__ cnts,
    const u64* __restrict__ bkeys, const float4* __restrict__ bboxes,
    u64* __restrict__ subk, u64* __restrict__ objk,
    float4* __restrict__ subb, float4* __restrict__ objb)
{
#pragma clang fp contract(off)
    const int c    = blockIdx.x;      // class 0..29
    const int b    = blockIdx.y;      // image
    const int lane = threadIdx.x;

    __shared__ u64    keyarr[BCAP];
    __shared__ u64    skey[BCAP];
    __shared__ float4 bxs4[BCAP];

    const size_t base = (size_t)b * NCLS + c;

    // ---- speculative parallel loads (masked by cnt below; garbage safe) ----
    u64    K1 = bkeys[base * BCAP + lane];
    float4 B1 = bboxes[base * BCAP + lane];
    u64 K2 = 0; float4 B2 = make_float4(0.f, 0.f, 0.f, 0.f);
    if (lane < BCAP - 64) {
        K2 = bkeys[base * BCAP + 64 + lane];
        B2 = bboxes[base * BCAP + 64 + lane];
    }
    const int cnt = cnts[base];                      // pre-clamped to BCAP
    float pv = pmax[lane & 31];                      // 32 per-image partials
    for (int off = 32; off; off >>= 1) pv = fmaxf(pv, __shfl_xor(pv, off));
    const float mco  = pv + 1.0f;                    // (max_coord + 1.0)
    const float offc = (float)c * mco;

    keyarr[lane] = K1;
    if (lane < BCAP - 64) keyarr[64 + lane] = K2;
    __threadfence_block();                           // in-wave LDS RAW

    // ---- rank-sort desc by unique key; scatter key AND box by rank ----
    {
        int r = 0;
        for (int l = 0; l < cnt; ++l) r += (keyarr[l] > K1) ? 1 : 0;
        if (lane < cnt) { skey[r] = K1; bxs4[r] = B1; }
    }
    if (cnt > 64) {                                  // rare second chunk
        int e = 64 + lane;
        int r = 0;
        for (int l = 0; l < cnt; ++l) r += (keyarr[l] > K2) ? 1 : 0;
        if (e < cnt) { skey[r] = K2; bxs4[r] = B2; }
    }
    __threadfence_block();

    // ---- sorted entries now in LDS ----
    const int  lim1  = (cnt < 64) ? cnt : 64;
    const bool have1 = (lane < lim1);
    u64 SK1 = have1 ? skey[lane] : 0;
    int idx1 = 1023 - (int)(unsigned)(SK1 & 0xffffffffull);
    float4 bj1 = have1 ? bxs4[lane] : make_float4(0.f, 0.f, 0.f, 0.f);
    const bool have2 = (64 + lane) < cnt;
    u64 SK2 = 0; int idx2 = 0; float4 bj2 = make_float4(0.f, 0.f, 0.f, 0.f);
    if (cnt > 64) {
        SK2 = have2 ? skey[64 + lane] : 0;
        idx2 = 1023 - (int)(unsigned)(SK2 & 0xffffffffull);
        if (have2) bj2 = bxs4[64 + lane];
    }

    // ---- chunk A: overlap masks + ballot resolve (verbatim decision body) --
    float j0 = bj1.x + offc, j1 = bj1.y + offc;
    float j2v = bj1.z + offc, j3 = bj1.w + offc;
    float aj = (j2v - j0) * (j3 - j1);
    u64 ov = 0;
    for (int l = 0; l < lim1; ++l) {
        float4 bl = bxs4[l];
        float i0 = bl.x + offc, i1 = bl.y + offc;
        float i2 = bl.z + offc, i3 = bl.w + offc;
        float ai = (i2 - i0) * (i3 - i1);
        if (have1 && l < lane) {
            float ltx = fmaxf(i0, j0), lty = fmaxf(i1, j1);
            float rbx = fminf(i2, j2v), rby = fminf(i3, j3);
            float wx = fmaxf(rbx - ltx, 0.0f), wy = fmaxf(rby - lty, 0.0f);
            float inter = wx * wy;
            float iou = inter / ((ai + aj) - inter);
            if (iou > 0.5f) ov |= (1ull << l);
        }
    }
    bool sup1 = !have1;
    for (int l = 0; l < lim1; ++l) {     // invariant: final for lanes <= l
        u64 bal = __ballot(sup1);
        if (!((bal >> l) & 1ull)) sup1 = sup1 || (((ov >> l) & 1ull) != 0ull);
    }
    const bool kept1 = have1 && !sup1;
    const u64 keptA = __ballot(kept1);

    // ---- chunk B (rare): entries 64..cnt-1 ----
    bool kept2 = false;
    if (cnt > 64) {
        float k0 = bj2.x + offc, k1 = bj2.y + offc;
        float k2 = bj2.z + offc, k3 = bj2.w + offc;
        float ak = (k2 - k0) * (k3 - k1);
        bool sup2 = !have2;
        for (int l = 0; l < 64; ++l) {               // vs kept chunk-A entries
            if ((keptA >> l) & 1ull) {
                float4 bl = bxs4[l];
                float i0 = bl.x + offc, i1 = bl.y + offc;
                float i2 = bl.z + offc, i3 = bl.w + offc;
                float ai = (i2 - i0) * (i3 - i1);
                if (!sup2) {
                    float ltx = fmaxf(i0, k0), lty = fmaxf(i1, k1);
                    float rbx = fminf(i2, k2), rby = fminf(i3, k3);
                    float wx = fmaxf(rbx - ltx, 0.0f), wy = fmaxf(rby - lty, 0.0f);
                    float inter = wx * wy;
                    float iou = inter / ((ai + ak) - inter);
                    if (iou > 0.5f) sup2 = true;
                }
            }
        }
        u64 ov2 = 0;
        const int lim2 = cnt - 64;
        for (int l = 0; l < lim2; ++l) {
            float4 bl = bxs4[64 + l];
            float i0 = bl.x + offc, i1 = bl.y + offc;
            float i2 = bl.z + offc, i3 = bl.w + offc;
            float ai = (i2 - i0) * (i3 - i1);
            if (have2 && l < lane) {
                float ltx = fmaxf(i0, k0), lty = fmaxf(i1, k1);
                float rbx = fminf(i2, k2), rby = fminf(i3, k3);
                float wx = fmaxf(rbx - ltx, 0.0f), wy = fmaxf(rby - lty, 0.0f);
                float inter = wx * wy;
                float iou = inter / ((ai + ak) - inter);
                if (iou > 0.5f) ov2 |= (1ull << l);
            }
        }
        for (int l = 0; l < lim2; ++l) {
            u64 bal = __ballot(sup2);
            if (!((bal >> l) & 1ull)) sup2 = sup2 || (((ov2 >> l) & 1ull) != 0ull);
        }
        kept2 = have2 && !sup2;
    }

    // ---- write first <=15 kept subject / object (key, box) for this class --
    const bool s1 = kept1 && (idx1 < NSUB), o1 = kept1 && (idx1 >= NSUB);
    const bool s2 = kept2 && (idx2 < NSUB), o2 = kept2 && (idx2 >= NSUB);
    const u64 mS1 = __ballot(s1), mS2 = __ballot(s2);
    const u64 mO1 = __ballot(o1), mO2 = __ballot(o2);
    const u64 ltm = (1ull << lane) - 1ull;
    u64*    subp = subk + base * 15;   float4* sbbp = subb + base * 15;
    u64*    objp = objk + base * 15;   float4* obbp = objb + base * 15;
    if (s1) { int p = (int)__popcll(mS1 & ltm); if (p < 15) { subp[p] = SK1; sbbp[p] = bj1; } }
    if (s2) { int p = (int)__popcll(mS1) + (int)__popcll(mS2 & ltm); if (p < 15) { subp[p] = SK2; sbbp[p] = bj2; } }
    if (o1) { int p = (int)__popcll(mO1 & ltm); if (p < 15) { objp[p] = SK1; obbp[p] = bj1; } }
    if (o2) { int p = (int)__popcll(mO1) + (int)__popcll(mO2 & ltm); if (p < 15) { objp[p] = SK2; obbp[p] = bj2; } }
    int tS = (int)(__popcll(mS1) + __popcll(mS2)); if (tS > 15) tS = 15;
    int tO = (int)(__popcll(mO1) + __popcll(mO2)); if (tO > 15) tO = 15;
    if (lane >= tS && lane < 15) subp[lane] = 0;   // key 0 = empty slot
    if (lane >= tO && lane < 15) objp[lane] = 0;   // (tail boxes never read)
}

// ------- Kernel 3: per-(image,side) top-15 via register argmax -------------
// Keys AND boxes come from the compact per-class kept lists written by K2:
// no global gathers inside the round loop (the old serial latency chain).
// label = slot/15 (the bucket class); score = high word of the key (exact).
__global__ __launch_bounds__(64) void select_kernel(
    const u64* __restrict__ subk, const u64* __restrict__ objk,
    const float4* __restrict__ subb, const float4* __restrict__ objb,
    float* __restrict__ out)
{
    const int b    = blockIdx.x;
    const int side = blockIdx.y;          // 0 = subjects, 1 = objects
    const int lane = threadIdx.x;

    float* outB = out;                    // [32][30][4]
    float* outS = out + BQ * KSLOT * 4;   // 3840
    float* outL = outS + BQ * KSLOT;      // 4800
    float* outN = outL + BQ * KSLOT;      // 5760
    float* outV = outN + BQ;              // 5792

    const u64*    src  = (side ? objk : subk) + (size_t)b * NCLS * 15;
    const float4* srcb = (side ? objb : subb) + (size_t)b * NCLS * 15;

    __shared__ float4 sbx[NCLS * 15];     // 7200 B: kept boxes, slot-indexed

    u64 kk[8];                            // strided: lane + 64*i  (covers 450)
    #pragma unroll
    for (int i = 0; i < 8; ++i) {
        int p = lane + 64 * i;
        kk[i] = (p < NCLS * 15) ? src[p] : 0;
    }
    for (int p = lane; p < NCLS * 15; p += 64) sbx[p] = srcb[p];
    __threadfence_block();                // in-wave LDS RAW

    int nvalid = 0;
    for (int r = 0; r < 15; ++r) {        // 15 argmax rounds (LDS/regs only)
        u64 lm = 0;
        #pragma unroll
        for (int i = 0; i < 8; ++i) lm = (kk[i] > lm) ? kk[i] : lm;
        u64 gm = lm;
        for (int off = 32; off; off >>= 1) {
            u64 o = __shfl_xor(gm, off);
            if (o > gm) gm = o;
        }
        int p = b * KSLOT + (side ? (15 + r) : r);
        if (gm == 0) {                    // no more candidates: empty slot
            if (lane == 0) {
                *(float4*)(outB + (size_t)p * 4) = make_float4(0.f, 0.f, 0.f, 0.f);
                outS[p] = 0.0f; outL[p] = -1.0f; outV[p] = 0.0f;
            }
        } else {
            u64 win = __ballot(lm == gm);          // keys unique if nonzero
            int wl = (int)__ffsll(win) - 1;
            if (lane == wl) {
                int sp = 0;                        // slot of gm (static idx)
                #pragma unroll
                for (int i = 0; i < 8; ++i) if (kk[i] == gm) sp = lane + 64 * i;
                #pragma unroll
                for (int i = 0; i < 8; ++i) if (kk[i] == gm) kk[i] = 0;  // consume
                float4 bx = sbx[sp];               // box carried through K2
                float score = __uint_as_float((unsigned)(gm >> 32));     // exact
                int cls = sp / 15;                 // label = bucket class
                *(float4*)(outB + (size_t)p * 4) = bx;
                outS[p] = score;
                outL[p] = (float)cls;
                outV[p] = 1.0f;
            }
            nvalid++;                              // uniform across lanes
        }
    }
    if (side == 0 && lane == 0) outN[b] = (float)nvalid; // = min(total_s,15)
}

extern "C" void kernel_launch(void* const* d_in, const int* in_sizes, int n_in,
                              void* d_out, int out_size, void* d_ws, size_t ws_size,
                              hipStream_t stream) {
    const float* sb = (const float*)d_in[0];
    const float* ss = (const float*)d_in[1];
    const int*   sl = (const int*)d_in[2];
    const float* ob = (const float*)d_in[3];
    const float* os = (const float*)d_in[4];
    const int*   ol = (const int*)d_in[5];

    // ws layout (~2.9 MB total; offsets 256-aligned)
    float*  pmax   = (float*)d_ws;                            // [32]
    int*    cnts   = (int*)((char*)d_ws + 256);               // [32][30]
    u64*    bkeys  = (u64*)((char*)d_ws + 8192);              // [32][30][96]
    float4* bboxes = (float4*)((char*)d_ws + 745472);         // [32][30][96]
    u64*    subk   = (u64*)((char*)d_ws + 2220032);           // [32][30][15]
    u64*    objk   = subk + (size_t)BQ * NCLS * 15;           // [32][30][15]
    float4* subb   = (float4*)((char*)d_ws + 2450432);        // [32][30][15]
    float4* objb   = subb + (size_t)BQ * NCLS * 15;           // [32][30][15]

    bucket_kernel<<<dim3(BQ), dim3(512), 0, stream>>>(
        sb, ss, sl, ob, os, ol, pmax, cnts, bkeys, bboxes);
    nms_class_kernel<<<dim3(NCLS, BQ), dim3(64), 0, stream>>>(
        pmax, cnts, bkeys, bboxes, subk, objk, subb, objb);
    select_kernel<<<dim3(BQ, 2), dim3(64), 0, stream>>>(
        subk, objk, subb, objb, (float*)d_out);
}